// Round 3
// baseline (303.905 us; speedup 1.0000x reference)
//
#include <hip/hip_runtime.h>
#include <math.h>

// FlowLayer: 2 steps of manifold (S^2) graph heat flow.
// N=50000 nodes, C=16 channels, D=3, E=1.6M edges.
//
// R20 = R19 build (unchanged) + f16 signal storage for the flow gathers.
// R19 post-mortem: source-level software pipeline was collapsed by the
// compiler (VGPR=36 proves loads were sunk back to uses); flowp floor
// ~60us across 8 structural variants is L2-MISS traffic on the random
// q-gather (FETCH 161MB vs 26MB compulsory; xin 9.6MB > 4MB per-XCD L2).
// R20 attacks bytes, not latency: gathered signal stored as f16
// ([node][c][d] halves, index node*48+c*3 -- same arithmetic as f32).
//  - nodes -> nodes_h conversion fused into scanCD.
//  - step1: p from nodes (f32), gathers from nodes_h, writes xtmp_h (f16
//    only -- no f32 intermediate at all).
//  - step2: p+gathers from xtmp_h, writes f32 out.
//  - all math stays f32; only storage is f16 (absmax budget 2e-2).
//  - nodes_h/xtmp_h live in the old boffL/xtmp 9.8MB region:
//    [0,4.8M) xtmp_h (written by flow1, after boffL dies at fill),
//    [4.8M,9.6M) nodes_h (written by scanCD; disjoint from boffL's live
//    2.45MB).
//
// NOTE: |u|^2 MUST be computed from u's components (not 1-cs^2): near
// antipodal pairs 1-cs^2 cancels catastrophically -> rsq explodes (R5 bug).

constexpr float EPS64F = 2.2204460492503131e-16f;  // np.float64 eps
constexpr float PI_F   = 3.14159265358979323846f;
constexpr int   SR_BITS = 14;                 // 16384-node subranges (64KB LDS)
constexpr int   CH_BITS = 15;                 // 32768-edge chunks

typedef int      vi4 __attribute__((ext_vector_type(4)));
typedef float    vf4 __attribute__((ext_vector_type(4)));
typedef float    vf2 __attribute__((ext_vector_type(2)));
typedef _Float16 vh4 __attribute__((ext_vector_type(4)));

// ---------------- CSR build ----------------

// LDS histogram: block (c = blockIdx.x, s = blockIdx.y).
__global__ __launch_bounds__(256) void lhist_kernel(
    const int* __restrict__ snd, unsigned char* __restrict__ pos,
    unsigned char* __restrict__ partial2, int E, int NC) {
  __shared__ int h[1 << SR_BITS];
  int tid = threadIdx.x;
  int c = blockIdx.x, s = blockIdx.y;
  for (int i = tid; i < (1 << SR_BITS); i += 256) h[i] = 0;
  __syncthreads();
  int base = c << CH_BITS;
  int cnt = min(1 << CH_BITS, E - base);
  int s0 = s << SR_BITS;
  const vi4* snd4 = (const vi4*)(snd + base);  // base is 32768-aligned
  int cnt4 = cnt >> 2;
  for (int i = tid; i < cnt4; i += 256) {
    vi4 sv = snd4[i];
    int e = base + (i << 2);
    int v;
    v = sv.x - s0; if ((unsigned)v < (1u << SR_BITS)) pos[e]     = (unsigned char)atomicAdd(&h[v], 1);
    v = sv.y - s0; if ((unsigned)v < (1u << SR_BITS)) pos[e + 1] = (unsigned char)atomicAdd(&h[v], 1);
    v = sv.z - s0; if ((unsigned)v < (1u << SR_BITS)) pos[e + 2] = (unsigned char)atomicAdd(&h[v], 1);
    v = sv.w - s0; if ((unsigned)v < (1u << SR_BITS)) pos[e + 3] = (unsigned char)atomicAdd(&h[v], 1);
  }
  if (tid == 0) {  // chunk tail (cnt % 4)
    for (int i = cnt4 << 2; i < cnt; ++i) {
      int v = snd[base + i] - s0;
      if ((unsigned)v < (1u << SR_BITS))
        pos[base + i] = (unsigned char)atomicAdd(&h[v], 1);
    }
  }
  __syncthreads();
  unsigned char* dst = partial2 + ((size_t)(s * NC + c) << SR_BITS);
  for (int i = tid; i < (1 << SR_BITS); i += 256)
    dst[i] = (unsigned char)h[i];
}

// Fused scan1+scanA with row padding: per-node exclusive fold over chunks
// (boffL in place, unpadded, uchar) -> degree; tile shfl-scan of PADDED
// degree (round up to 16) -> tile-local exclusive row_start + tile totals.
__global__ __launch_bounds__(1024) void scan1A_kernel(
    const unsigned char* __restrict__ partial2, unsigned char* __restrict__ boffL,
    int* __restrict__ row_start, int* __restrict__ btot, int N, int NC) {
  __shared__ int wsum[16];
  int tid = threadIdx.x;
  int lane = tid & 63, wave = tid >> 6;
  int i = blockIdx.x * 1024 + tid;
  int vpad = 0;
  if (i < N) {
    int s = i >> SR_BITS, lv = i & ((1 << SR_BITS) - 1);
    int run = 0;
    for (int c = 0; c < NC; ++c) {
      int t = partial2[((size_t)(s * NC + c) << SR_BITS) + lv];
      boffL[(size_t)c * N + i] = (unsigned char)run;  // run <= degree <= ~80
      run += t;
    }
    vpad = (run + 15) & ~15;  // padded degree
  }
  int incl = vpad;
  #pragma unroll
  for (int off = 1; off < 64; off <<= 1) {
    int t = __shfl_up(incl, off, 64);
    if (lane >= off) incl += t;
  }
  if (lane == 63) wsum[wave] = incl;
  __syncthreads();
  if (wave == 0 && lane < 16) {
    int wincl = wsum[lane];
    #pragma unroll
    for (int off = 1; off < 16; off <<= 1) {
      int t = __shfl_up(wincl, off, 64);
      if (lane >= off) wincl += t;
    }
    wsum[lane] = wincl;
  }
  __syncthreads();
  int woff = (wave > 0) ? wsum[wave - 1] : 0;
  if (i < N) row_start[i] = woff + incl - vpad;  // tile-local exclusive
  if (tid == 0) btot[blockIdx.x] = wsum[15];
}

// scanCD (+ folded scanB): each block wave-scans the <=64 tile totals in
// LDS, then finalizes row_start. Fused: nodes(f32) -> nodes_h(f16) convert
// (grid-stride, vh4 8B stores).
__global__ __launch_bounds__(256) void scanCD_kernel(
    int* __restrict__ row_start, const int* __restrict__ btot,
    const vf4* __restrict__ nodes4, _Float16* __restrict__ nodes_h,
    int N, int nb) {
  __shared__ int bsh[64];
  int tid = threadIdx.x;
  if (tid < 64) {
    int v = (tid < nb) ? btot[tid] : 0;
    int incl = v;
    #pragma unroll
    for (int off = 1; off < 64; off <<= 1) {
      int t = __shfl_up(incl, off, 64);
      if (tid >= off) incl += t;
    }
    bsh[tid] = incl - v;  // exclusive tile offset
    if (blockIdx.x == 0 && tid == 63) row_start[N] = incl;  // padded total
  }
  __syncthreads();
  int i = blockIdx.x * 256 + tid;
  if (i < N) row_start[i] = row_start[i] + bsh[i >> 10];
  // fused f32 -> f16 conversion: N*12 float4 groups (N*48 floats)
  int total = N * 12;
  for (int idx = blockIdx.x * 256 + tid; idx < total; idx += gridDim.x * 256) {
    vf4 v = nodes4[idx];
    vh4 h = {(_Float16)v.x, (_Float16)v.y, (_Float16)v.z, (_Float16)v.w};
    ((vh4*)nodes_h)[idx] = h;
  }
}

// Atomic-free fill: slot = row_start[snd] + boffL[chunk][snd] + pos[e];
// packs (w, rcv*48). Pad slots (row tails) stay zero from the memset.
// row_start (200KB) and the chunk's boffL slice (50KB) are L2-resident.
__global__ __launch_bounds__(256) void fill_kernel(
    const vi4* __restrict__ snd4, const vi4* __restrict__ rcv4,
    const vf4* __restrict__ ew4, const unsigned char* __restrict__ pos,
    const unsigned char* __restrict__ boffL, const int* __restrict__ row_start,
    long long* __restrict__ pair,
    const int* __restrict__ snd, const int* __restrict__ rcv,
    const float* __restrict__ ew, int N, int E) {
  int tid = threadIdx.x;
  int E4 = E >> 2;
  #pragma unroll
  for (int gg = 0; gg < 2; ++gg) {
    int g = blockIdx.x * 512 + gg * 256 + tid;
    if (g < E4) {
      int e = g << 2;
      const unsigned char* bc = boffL + (size_t)(e >> CH_BITS) * N;  // same chunk e..e+3
      vi4 s = __builtin_nontemporal_load(&snd4[g]);
      vi4 r = __builtin_nontemporal_load(&rcv4[g]);
      vf4 w = __builtin_nontemporal_load(&ew4[g]);
      unsigned pb = *(const unsigned*)(pos + e);
      int rs0 = row_start[s.x] + bc[s.x];
      int rs1 = row_start[s.y] + bc[s.y];
      int rs2 = row_start[s.z] + bc[s.z];
      int rs3 = row_start[s.w] + bc[s.w];
      pair[rs0 + (pb & 255u)] =
          (long long)(((unsigned long long)(unsigned)__float_as_int(w.x) << 32) | (unsigned)(r.x * 48));
      pair[rs1 + ((pb >> 8) & 255u)] =
          (long long)(((unsigned long long)(unsigned)__float_as_int(w.y) << 32) | (unsigned)(r.y * 48));
      pair[rs2 + ((pb >> 16) & 255u)] =
          (long long)(((unsigned long long)(unsigned)__float_as_int(w.z) << 32) | (unsigned)(r.z * 48));
      pair[rs3 + (pb >> 24)] =
          (long long)(((unsigned long long)(unsigned)__float_as_int(w.w) << 32) | (unsigned)(r.w * 48));
    }
  }
  if (blockIdx.x == 0 && tid == 0) {
    for (int e = E4 << 2; e < E; ++e) {  // edge tail
      int sn = snd[e];
      pair[row_start[sn] + boffL[(size_t)(e >> CH_BITS) * N + sn] + pos[e]] =
          (long long)(((unsigned long long)(unsigned)__float_as_int(ew[e]) << 32) | (unsigned)(rcv[e] * 48));
    }
  }
}

// ---------------- flow (R10 flowp math, f16 gather storage) ----------------

__device__ __forceinline__ void edge_accum_pk(
    vf2 p0, vf2 p1, vf2 p2, vf2 q0, vf2 q1, vf2 q2, vf2 w,
    vf2& a0, vf2& a1, vf2& a2) {
  vf2 cs = p0 * q0 + p1 * q1 + p2 * q2;
  cs = __builtin_elementwise_min(vf2{1.f, 1.f},
       __builtin_elementwise_max(vf2{-1.f, -1.f}, cs));
  vf2 u0 = q0 - cs * p0;
  vf2 u1 = q1 - cs * p1;
  vf2 u2 = q2 - cs * p2;
  // |u|^2 from components (R5 lesson)
  vf2 un2 = __builtin_elementwise_max(u0 * u0 + u1 * u1 + u2 * u2,
                                      vf2{1e-24f, 1e-24f});
  // acos via A&S 4.4.45 (|err| <= 6.7e-5; output threshold is 2e-2)
  vf2 ax = __builtin_elementwise_abs(cs);
  vf2 s = __builtin_elementwise_sqrt(vf2{1.f, 1.f} - ax);
  vf2 poly = ((ax * -0.0187293f + 0.0742610f) * ax - 0.2121144f) * ax
             + 1.5707288f;
  vf2 th = s * poly;
  vf2 theta;
  theta.x = (cs.x >= 0.0f) ? th.x : (PI_F - th.x);
  theta.y = (cs.y >= 0.0f) ? th.y : (PI_F - th.y);
  vf2 rsq;
  rsq.x = __builtin_amdgcn_rsqf(un2.x);
  rsq.y = __builtin_amdgcn_rsqf(un2.y);
  vf2 coef = w * theta * rsq;
  a0 += coef * u0;
  a1 += coef * u1;
  a2 += coef * u2;
}

__device__ __forceinline__ void node_step(
    float a0, float a1, float a2, float ws, float p0, float p1, float p2,
    float ts, float dsv, float& y0, float& y1, float& y2) {
  // v_lap = -agg/deg; nrm/scale sign-invariant; -(v_lap*scale)*t = +g*scale*t
  float invdg = __builtin_amdgcn_rcpf(ws + 1e-12f);
  float g0 = a0 * invdg, g1 = a1 * invdg, g2 = a2 * invdg;
  float nrm = sqrtf(fmaf(g0, g0, fmaf(g1, g1, g2 * g2)) + EPS64F);
  float tch = ts * ts * 0.5f;  // t_sqrt^2 / N_STEPS
  float dch = dsv * dsv;
  float alp = __builtin_amdgcn_rcpf(1.0f + __expf(dch - nrm));  // sigmoid
  float scale = (nrm * alp <= 1.0f) ? alp : __builtin_amdgcn_rcpf(nrm);
  float f = scale * tch;
  float v0 = g0 * f, v1 = g1 * f, v2 = g2 * f;
  float nv = sqrtf(fmaf(v0, v0, fmaf(v1, v1, v2 * v2)));
  float cn = __cosf(nv);
  float sc = (nv > 1e-20f) ? (__sinf(nv) * __builtin_amdgcn_rcpf(nv)) : 1.0f;
  float t0 = fmaf(cn, p0, sc * v0);
  float t1 = fmaf(cn, p1, sc * v1);
  float t2 = fmaf(cn, p2, sc * v2);
  float inv = __builtin_amdgcn_rsqf(fmaf(t0, t0, fmaf(t1, t1, t2 * t2)));
  y0 = t0 * inv; y1 = t1 * inv; y2 = t2 * inv;
}

// Wave per node; lane = k*16+c; rows padded to 16 -> no guards: pads are
// (w=0, rcv=0) entries, full-lane loads always in-bounds.
// Gathers read f16 records (node*48 + c*3 half index -- same arithmetic as
// f32). p from pf (f32, step1) or xh (f16, step2). Output to of (f32,
// step2) or oh (f16 intermediate, step1). All math f32.
__global__ __launch_bounds__(256, 8) void flowp_kernel(
    const _Float16* __restrict__ xh, const float* __restrict__ pf,
    const int* __restrict__ row_start, const long long* __restrict__ pair,
    const float* __restrict__ tsq, const float* __restrict__ dsq,
    float* __restrict__ of, _Float16* __restrict__ oh, int N) {
  int node = blockIdx.x * 4 + (threadIdx.x >> 6);
  if (node >= N) return;
  int lane = threadIdx.x & 63;
  int c = lane & 15;
  int k = lane >> 4;
  int c3 = c * 3;
  int beg = row_start[node];
  int end = row_start[node + 1];
  int ip = node * 48 + c3;
  float ps0, ps1, ps2;
  if (pf) {
    ps0 = pf[ip]; ps1 = pf[ip + 1]; ps2 = pf[ip + 2];
  } else {
    ps0 = (float)xh[ip]; ps1 = (float)xh[ip + 1]; ps2 = (float)xh[ip + 2];
  }
  vf2 p0 = {ps0, ps0}, p1 = {ps1, ps1}, p2 = {ps2, ps2};
  vf2 a0 = {0.f, 0.f}, a1 = {0.f, 0.f}, a2 = {0.f, 0.f}, wsv = {0.f, 0.f};
  int iters = (end - beg) >> 4;  // exact (rows padded to 16)
  int j = beg + k;
  for (int t = 0; t < iters; ++t, j += 16) {
    long long e0 = __builtin_nontemporal_load(&pair[j]);
    long long e1 = __builtin_nontemporal_load(&pair[j + 4]);
    long long e2 = __builtin_nontemporal_load(&pair[j + 8]);
    long long e3 = __builtin_nontemporal_load(&pair[j + 12]);
    float w0 = __int_as_float((int)(e0 >> 32));
    float w1 = __int_as_float((int)(e1 >> 32));
    float w2 = __int_as_float((int)(e2 >> 32));
    float w3 = __int_as_float((int)(e3 >> 32));
    const _Float16* qp;
    qp = xh + ((int)e0 + c3); float qa0 = qp[0], qa1 = qp[1], qa2 = qp[2];
    qp = xh + ((int)e1 + c3); float qb0 = qp[0], qb1 = qp[1], qb2 = qp[2];
    qp = xh + ((int)e2 + c3); float qc0 = qp[0], qc1 = qp[1], qc2 = qp[2];
    qp = xh + ((int)e3 + c3); float qd0 = qp[0], qd1 = qp[1], qd2 = qp[2];
    vf2 wA = {w0, w1}, wB = {w2, w3};
    edge_accum_pk(p0, p1, p2, vf2{qa0, qb0}, vf2{qa1, qb1},
                  vf2{qa2, qb2}, wA, a0, a1, a2);
    edge_accum_pk(p0, p1, p2, vf2{qc0, qd0}, vf2{qc1, qd1},
                  vf2{qc2, qd2}, wB, a0, a1, a2);
    wsv += wA + wB;
  }
  float A0 = a0.x + a0.y, A1 = a1.x + a1.y, A2 = a2.x + a2.y;
  float ws = wsv.x + wsv.y;
  A0 += __shfl_xor(A0, 16); A1 += __shfl_xor(A1, 16);
  A2 += __shfl_xor(A2, 16); ws += __shfl_xor(ws, 16);
  A0 += __shfl_xor(A0, 32); A1 += __shfl_xor(A1, 32);
  A2 += __shfl_xor(A2, 32); ws += __shfl_xor(ws, 32);
  if (k == 0) {
    float y0, y1, y2;
    node_step(A0, A1, A2, ws, ps0, ps1, ps2, tsq[c], dsq[c], y0, y1, y2);
    if (of) { of[ip] = y0; of[ip + 1] = y1; of[ip + 2] = y2; }
    if (oh) {
      oh[ip]     = (_Float16)y0;
      oh[ip + 1] = (_Float16)y1;
      oh[ip + 2] = (_Float16)y2;
    }
  }
}

static inline size_t al16(size_t x) { return (x + 15) & ~(size_t)15; }

extern "C" void kernel_launch(void* const* d_in, const int* in_sizes, int n_in,
                              void* d_out, int out_size, void* d_ws, size_t ws_size,
                              hipStream_t stream) {
  const float* nodes = (const float*)d_in[0];  // [N,16,3]
  const float* ew    = (const float*)d_in[1];  // [E]
  const float* tsq   = (const float*)d_in[2];  // [16]
  const float* dsq   = (const float*)d_in[3];  // [16]
  const int*   snd   = (const int*)d_in[4];    // [E]
  const int*   rcv   = (const int*)d_in[5];    // [E]
  float* out = (float*)d_out;

  int E = in_sizes[1];
  int N = in_sizes[0] / 48;

  int NS = (N + (1 << SR_BITS) - 1) >> SR_BITS;  // node subranges (4)
  int NC = (E + (1 << CH_BITS) - 1) >> CH_BITS;  // edge chunks (49)

  // workspace (~34MB): row_start[N+4] | aux | pair[E+15N+64] | partial2(uchar)
  //                    | boffL-region | pos[E bytes]
  // boffL-region (>= max(NC*N, 2*al16(N*96))): boffL uchar [0,NC*N) live
  // scan1A->fill; xtmp_h f16 [0,N*96) written by flow1 (after fill);
  // nodes_h f16 [al16(N*96), 2*al16(N*96)) written by scanCD (disjoint
  // from live boffL: al16(N*96) ~ 4.8MB > NC*N ~ 2.45MB).
  size_t padN  = (size_t)E + 15 * (size_t)N + 64;  // >= padded total + slack
  size_t rsB   = al16((size_t)(N + 4) * 4);
  size_t auxB  = 512;
  size_t pairB = al16(padN * 8);
  size_t p2B   = al16((size_t)NS * NC << SR_BITS);  // uchar
  size_t xhB   = al16((size_t)N * 96);              // one f16 signal buffer
  size_t boffB = al16((size_t)NC * N * 4);
  if (boffB < 2 * xhB) boffB = 2 * xhB;

  char* base = (char*)d_ws;
  int*           row_start = (int*)base;
  int*           btot      = (int*)(base + rsB);
  long long*     pair      = (long long*)(base + rsB + auxB);
  unsigned char* partial2  = (unsigned char*)(base + rsB + auxB + pairB);
  unsigned char* boffL     = (unsigned char*)(base + rsB + auxB + pairB + p2B);
  unsigned char* pos       = (unsigned char*)(base + rsB + auxB + pairB + p2B + boffB);
  _Float16*      xtmp_h    = (_Float16*)boffL;           // [0, N*96) after fill
  _Float16*      nodes_h   = (_Float16*)((char*)boffL + xhB);

  int E4  = E >> 2;
  int nb  = (N + 1023) / 1024;   // tiles (<=64 required; 49 @ N=50K)
  int nb2 = (N + 255) / 256;
  int fbk = (E4 + 511) / 512;
  int nfb = (N + 3) / 4;

  hipMemsetAsync(pair, 0, pairB, stream);  // zero pad slots (w=0, rcv=0)
  lhist_kernel<<<dim3(NC, NS), 256, 0, stream>>>(snd, pos, partial2, E, NC);
  scan1A_kernel<<<nb, 1024, 0, stream>>>(partial2, boffL, row_start, btot, N, NC);
  scanCD_kernel<<<nb2, 256, 0, stream>>>(row_start, btot, (const vf4*)nodes,
                                         nodes_h, N, nb);
  fill_kernel<<<fbk, 256, 0, stream>>>((const vi4*)snd, (const vi4*)rcv,
                                       (const vf4*)ew, pos, boffL, row_start,
                                       pair, snd, rcv, ew, N, E);

  // step 1: nodes_h -> xtmp_h (p from f32 nodes); step 2: xtmp_h -> out
  flowp_kernel<<<nfb, 256, 0, stream>>>(nodes_h, nodes, row_start, pair,
                                        tsq, dsq, nullptr, xtmp_h, N);
  flowp_kernel<<<nfb, 256, 0, stream>>>(xtmp_h, nullptr, row_start, pair,
                                        tsq, dsq, out, nullptr, N);
}

// Round 4
// 270.927 us; speedup vs baseline: 1.1217x; 1.1217x over previous
//
#include <hip/hip_runtime.h>
#include <math.h>

// FlowLayer: 2 steps of manifold (S^2) graph heat flow.
// N=50000 nodes, C=16, D=3, E=1.6M edges.
//
// R21 = R19 build + two byte/request reductions informed by R20's failure:
//  - R20 lesson: flowp is NOT miss-byte-bound (FETCH 161->57MB made it
//    SLOWER, 61->73.7us): the 6B unaligned f16 records tripled gather
//    instructions (ushort x3). Bottleneck = VMEM request count / latency.
//  - R21 q-records: f16x4 PADDED 8B [node*16+c] -> ONE dwordx2 per gather
//    (vs dwordx3 f32), 128B/edge-wave (vs 192), 2 lines/gather (vs 3).
//  - R21 pair entries: 4B packed (w 15-bit fixed | rcv 17-bit). Fixed-pt w
//    abs err 1.5e-5, enters a w-normalized mean -> negligible. Halves pair
//    stream, memset, and fill scatter footprint.
//  - Precision insurance vs R20 (absmax 0.0195): only gathered q is f16.
//    step1 writes f32 result to d_out (scratch) AND f16 xtmp_h4; step2
//    reads p from f32 d_out, gathers f16, overwrites d_out. p-base and
//    intermediate stay f32.
//  - f16 buffers carved from dead partial2+boffL region (13.0MB >= 12.8):
//    xtmp_h4 [0,6.4M) written by flow1 (after fill; partial2/boffL dead),
//    nodes_h4 [6.4,12.8M) written by scanCD (disjoint from live boffL
//    [3.2,5.65M) and pos [13.0M,..)).
// R18 lesson kept: no aggregate locals in flowp (scalars/ext_vector only).
//
// NOTE: |u|^2 MUST be computed from u's components (not 1-cs^2): near
// antipodal pairs 1-cs^2 cancels catastrophically -> rsq explodes (R5 bug).

constexpr float EPS64F = 2.2204460492503131e-16f;  // np.float64 eps
constexpr float PI_F   = 3.14159265358979323846f;
constexpr int   SR_BITS = 14;                 // 16384-node subranges (64KB LDS)
constexpr int   CH_BITS = 15;                 // 32768-edge chunks

typedef int      vi4 __attribute__((ext_vector_type(4)));
typedef float    vf4 __attribute__((ext_vector_type(4)));
typedef float    vf2 __attribute__((ext_vector_type(2)));
typedef _Float16 vh4 __attribute__((ext_vector_type(4)));

// ---------------- CSR build ----------------

// LDS histogram: block (c = blockIdx.x, s = blockIdx.y).
__global__ __launch_bounds__(256) void lhist_kernel(
    const int* __restrict__ snd, unsigned char* __restrict__ pos,
    unsigned char* __restrict__ partial2, int E, int NC) {
  __shared__ int h[1 << SR_BITS];
  int tid = threadIdx.x;
  int c = blockIdx.x, s = blockIdx.y;
  for (int i = tid; i < (1 << SR_BITS); i += 256) h[i] = 0;
  __syncthreads();
  int base = c << CH_BITS;
  int cnt = min(1 << CH_BITS, E - base);
  int s0 = s << SR_BITS;
  const vi4* snd4 = (const vi4*)(snd + base);  // base is 32768-aligned
  int cnt4 = cnt >> 2;
  for (int i = tid; i < cnt4; i += 256) {
    vi4 sv = snd4[i];
    int e = base + (i << 2);
    int v;
    v = sv.x - s0; if ((unsigned)v < (1u << SR_BITS)) pos[e]     = (unsigned char)atomicAdd(&h[v], 1);
    v = sv.y - s0; if ((unsigned)v < (1u << SR_BITS)) pos[e + 1] = (unsigned char)atomicAdd(&h[v], 1);
    v = sv.z - s0; if ((unsigned)v < (1u << SR_BITS)) pos[e + 2] = (unsigned char)atomicAdd(&h[v], 1);
    v = sv.w - s0; if ((unsigned)v < (1u << SR_BITS)) pos[e + 3] = (unsigned char)atomicAdd(&h[v], 1);
  }
  if (tid == 0) {  // chunk tail (cnt % 4)
    for (int i = cnt4 << 2; i < cnt; ++i) {
      int v = snd[base + i] - s0;
      if ((unsigned)v < (1u << SR_BITS))
        pos[base + i] = (unsigned char)atomicAdd(&h[v], 1);
    }
  }
  __syncthreads();
  unsigned char* dst = partial2 + ((size_t)(s * NC + c) << SR_BITS);
  for (int i = tid; i < (1 << SR_BITS); i += 256)
    dst[i] = (unsigned char)h[i];
}

// Fused scan1+scanA with row padding: per-node exclusive fold over chunks
// (boffL in place, unpadded, uchar) -> degree; tile shfl-scan of PADDED
// degree (round up to 16) -> tile-local exclusive row_start + tile totals.
__global__ __launch_bounds__(1024) void scan1A_kernel(
    const unsigned char* __restrict__ partial2, unsigned char* __restrict__ boffL,
    int* __restrict__ row_start, int* __restrict__ btot, int N, int NC) {
  __shared__ int wsum[16];
  int tid = threadIdx.x;
  int lane = tid & 63, wave = tid >> 6;
  int i = blockIdx.x * 1024 + tid;
  int vpad = 0;
  if (i < N) {
    int s = i >> SR_BITS, lv = i & ((1 << SR_BITS) - 1);
    int run = 0;
    for (int c = 0; c < NC; ++c) {
      int t = partial2[((size_t)(s * NC + c) << SR_BITS) + lv];
      boffL[(size_t)c * N + i] = (unsigned char)run;  // run <= degree <= ~80
      run += t;
    }
    vpad = (run + 15) & ~15;  // padded degree
  }
  int incl = vpad;
  #pragma unroll
  for (int off = 1; off < 64; off <<= 1) {
    int t = __shfl_up(incl, off, 64);
    if (lane >= off) incl += t;
  }
  if (lane == 63) wsum[wave] = incl;
  __syncthreads();
  if (wave == 0 && lane < 16) {
    int wincl = wsum[lane];
    #pragma unroll
    for (int off = 1; off < 16; off <<= 1) {
      int t = __shfl_up(wincl, off, 64);
      if (lane >= off) wincl += t;
    }
    wsum[lane] = wincl;
  }
  __syncthreads();
  int woff = (wave > 0) ? wsum[wave - 1] : 0;
  if (i < N) row_start[i] = woff + incl - vpad;  // tile-local exclusive
  if (tid == 0) btot[blockIdx.x] = wsum[15];
}

// scanCD: wave-scan of <=64 tile totals -> finalize row_start. Fused:
// nodes(f32 [node][c][3]) -> nodes_h4 (f16x4 8B [node*16+c]) conversion.
__global__ __launch_bounds__(256) void scanCD_kernel(
    int* __restrict__ row_start, const int* __restrict__ btot,
    const float* __restrict__ nodes, vh4* __restrict__ nodes_h4,
    int N, int nb) {
  __shared__ int bsh[64];
  int tid = threadIdx.x;
  if (tid < 64) {
    int v = (tid < nb) ? btot[tid] : 0;
    int incl = v;
    #pragma unroll
    for (int off = 1; off < 64; off <<= 1) {
      int t = __shfl_up(incl, off, 64);
      if (tid >= off) incl += t;
    }
    bsh[tid] = incl - v;  // exclusive tile offset
    if (blockIdx.x == 0 && tid == 63) row_start[N] = incl;  // padded total
  }
  __syncthreads();
  int i = blockIdx.x * 256 + tid;
  if (i < N) row_start[i] = row_start[i] + bsh[i >> 10];
  // fused f32 -> f16x4 conversion: N*16 records (consecutive 12B reads
  // across consecutive threads -> coalesced; 8B writes -> coalesced).
  int total = N * 16;
  for (int idx = blockIdx.x * 256 + tid; idx < total; idx += gridDim.x * 256) {
    const float* s = nodes + idx * 3;
    vh4 h = {(_Float16)s[0], (_Float16)s[1], (_Float16)s[2], (_Float16)0.f};
    nodes_h4[idx] = h;
  }
}

// Atomic-free fill: slot = row_start[snd] + boffL[chunk][snd] + pos[e];
// packs 4B (w15 fixed << 17 | rcv). Pad slots stay zero from the memset
// (w=0, rcv=0). row_start + chunk's boffL slice are L2-resident.
__global__ __launch_bounds__(256) void fill_kernel(
    const vi4* __restrict__ snd4, const vi4* __restrict__ rcv4,
    const vf4* __restrict__ ew4, const unsigned char* __restrict__ pos,
    const unsigned char* __restrict__ boffL, const int* __restrict__ row_start,
    int* __restrict__ pair,
    const int* __restrict__ snd, const int* __restrict__ rcv,
    const float* __restrict__ ew, int N, int E) {
  int tid = threadIdx.x;
  int E4 = E >> 2;
  #pragma unroll
  for (int gg = 0; gg < 2; ++gg) {
    int g = blockIdx.x * 512 + gg * 256 + tid;
    if (g < E4) {
      int e = g << 2;
      const unsigned char* bc = boffL + (size_t)(e >> CH_BITS) * N;  // same chunk e..e+3
      vi4 s = __builtin_nontemporal_load(&snd4[g]);
      vi4 r = __builtin_nontemporal_load(&rcv4[g]);
      vf4 w = __builtin_nontemporal_load(&ew4[g]);
      unsigned pb = *(const unsigned*)(pos + e);
      int rs0 = row_start[s.x] + bc[s.x];
      int rs1 = row_start[s.y] + bc[s.y];
      int rs2 = row_start[s.z] + bc[s.z];
      int rs3 = row_start[s.w] + bc[s.w];
      unsigned e0 = ((unsigned)(int)fmaf(w.x, 32767.f, 0.5f) << 17) | (unsigned)r.x;
      unsigned e1 = ((unsigned)(int)fmaf(w.y, 32767.f, 0.5f) << 17) | (unsigned)r.y;
      unsigned e2 = ((unsigned)(int)fmaf(w.z, 32767.f, 0.5f) << 17) | (unsigned)r.z;
      unsigned e3 = ((unsigned)(int)fmaf(w.w, 32767.f, 0.5f) << 17) | (unsigned)r.w;
      pair[rs0 + (pb & 255u)]         = (int)e0;
      pair[rs1 + ((pb >> 8) & 255u)]  = (int)e1;
      pair[rs2 + ((pb >> 16) & 255u)] = (int)e2;
      pair[rs3 + (pb >> 24)]          = (int)e3;
    }
  }
  if (blockIdx.x == 0 && tid == 0) {
    for (int e = E4 << 2; e < E; ++e) {  // edge tail
      int sn = snd[e];
      pair[row_start[sn] + boffL[(size_t)(e >> CH_BITS) * N + sn] + pos[e]] =
          (int)(((unsigned)(int)fmaf(ew[e], 32767.f, 0.5f) << 17) | (unsigned)rcv[e]);
    }
  }
}

// ---------------- flow (R10 flowp math, f16x4 gathers, 4B pair) ----------------

__device__ __forceinline__ void edge_accum_pk(
    vf2 p0, vf2 p1, vf2 p2, vf2 q0, vf2 q1, vf2 q2, vf2 w,
    vf2& a0, vf2& a1, vf2& a2) {
  vf2 cs = p0 * q0 + p1 * q1 + p2 * q2;
  cs = __builtin_elementwise_min(vf2{1.f, 1.f},
       __builtin_elementwise_max(vf2{-1.f, -1.f}, cs));
  vf2 u0 = q0 - cs * p0;
  vf2 u1 = q1 - cs * p1;
  vf2 u2 = q2 - cs * p2;
  // |u|^2 from components (R5 lesson)
  vf2 un2 = __builtin_elementwise_max(u0 * u0 + u1 * u1 + u2 * u2,
                                      vf2{1e-24f, 1e-24f});
  // acos via A&S 4.4.45 (|err| <= 6.7e-5; output threshold is 2e-2)
  vf2 ax = __builtin_elementwise_abs(cs);
  vf2 s = __builtin_elementwise_sqrt(vf2{1.f, 1.f} - ax);
  vf2 poly = ((ax * -0.0187293f + 0.0742610f) * ax - 0.2121144f) * ax
             + 1.5707288f;
  vf2 th = s * poly;
  vf2 theta;
  theta.x = (cs.x >= 0.0f) ? th.x : (PI_F - th.x);
  theta.y = (cs.y >= 0.0f) ? th.y : (PI_F - th.y);
  vf2 rsq;
  rsq.x = __builtin_amdgcn_rsqf(un2.x);
  rsq.y = __builtin_amdgcn_rsqf(un2.y);
  vf2 coef = w * theta * rsq;
  a0 += coef * u0;
  a1 += coef * u1;
  a2 += coef * u2;
}

__device__ __forceinline__ void node_step(
    float a0, float a1, float a2, float ws, float p0, float p1, float p2,
    float ts, float dsv, float& y0, float& y1, float& y2) {
  // v_lap = -agg/deg; nrm/scale sign-invariant; -(v_lap*scale)*t = +g*scale*t
  float invdg = __builtin_amdgcn_rcpf(ws + 1e-12f);
  float g0 = a0 * invdg, g1 = a1 * invdg, g2 = a2 * invdg;
  float nrm = sqrtf(fmaf(g0, g0, fmaf(g1, g1, g2 * g2)) + EPS64F);
  float tch = ts * ts * 0.5f;  // t_sqrt^2 / N_STEPS
  float dch = dsv * dsv;
  float alp = __builtin_amdgcn_rcpf(1.0f + __expf(dch - nrm));  // sigmoid
  float scale = (nrm * alp <= 1.0f) ? alp : __builtin_amdgcn_rcpf(nrm);
  float f = scale * tch;
  float v0 = g0 * f, v1 = g1 * f, v2 = g2 * f;
  float nv = sqrtf(fmaf(v0, v0, fmaf(v1, v1, v2 * v2)));
  float cn = __cosf(nv);
  float sc = (nv > 1e-20f) ? (__sinf(nv) * __builtin_amdgcn_rcpf(nv)) : 1.0f;
  float t0 = fmaf(cn, p0, sc * v0);
  float t1 = fmaf(cn, p1, sc * v1);
  float t2 = fmaf(cn, p2, sc * v2);
  float inv = __builtin_amdgcn_rsqf(fmaf(t0, t0, fmaf(t1, t1, t2 * t2)));
  y0 = t0 * inv; y1 = t1 * inv; y2 = t2 * inv;
}

// Wave per node; lane = k*16+c; rows padded to 16 -> no guards: pads are
// (w=0, rcv=0) entries, always in-bounds.
// pair entry: 4B (w15<<17 | rcv). q gather: ONE dwordx2 from f16x4 records
// xh4[rcv*16+c]. p from f32 pf (nodes in step1, d_out-scratch in step2).
// Writes: of (f32, always) + oh4 (f16x4, step1 only). All math f32.
__global__ __launch_bounds__(256, 8) void flowp_kernel(
    const vh4* __restrict__ xh4, const float* __restrict__ pf,
    const int* __restrict__ row_start, const int* __restrict__ pair,
    const float* __restrict__ tsq, const float* __restrict__ dsq,
    float* __restrict__ of, vh4* __restrict__ oh4, int N) {
  int node = blockIdx.x * 4 + (threadIdx.x >> 6);
  if (node >= N) return;
  int lane = threadIdx.x & 63;
  int c = lane & 15;
  int k = lane >> 4;
  int c3 = c * 3;
  int beg = row_start[node];
  int end = row_start[node + 1];
  int ip = node * 48 + c3;
  float ps0 = pf[ip], ps1 = pf[ip + 1], ps2 = pf[ip + 2];
  vf2 p0 = {ps0, ps0}, p1 = {ps1, ps1}, p2 = {ps2, ps2};
  vf2 a0 = {0.f, 0.f}, a1 = {0.f, 0.f}, a2 = {0.f, 0.f}, wsv = {0.f, 0.f};
  int iters = (end - beg) >> 4;  // exact (rows padded to 16)
  int j = beg + k;
  constexpr float WS = 1.0f / 32767.0f;
  for (int t = 0; t < iters; ++t, j += 16) {
    int e0 = __builtin_nontemporal_load(&pair[j]);
    int e1 = __builtin_nontemporal_load(&pair[j + 4]);
    int e2 = __builtin_nontemporal_load(&pair[j + 8]);
    int e3 = __builtin_nontemporal_load(&pair[j + 12]);
    float w0 = (float)((unsigned)e0 >> 17) * WS;
    float w1 = (float)((unsigned)e1 >> 17) * WS;
    float w2 = (float)((unsigned)e2 >> 17) * WS;
    float w3 = (float)((unsigned)e3 >> 17) * WS;
    vh4 qva = xh4[((e0 & 0x1FFFF) << 4) + c];
    vh4 qvb = xh4[((e1 & 0x1FFFF) << 4) + c];
    vh4 qvc = xh4[((e2 & 0x1FFFF) << 4) + c];
    vh4 qvd = xh4[((e3 & 0x1FFFF) << 4) + c];
    float qa0 = (float)qva.x, qa1 = (float)qva.y, qa2 = (float)qva.z;
    float qb0 = (float)qvb.x, qb1 = (float)qvb.y, qb2 = (float)qvb.z;
    float qc0 = (float)qvc.x, qc1 = (float)qvc.y, qc2 = (float)qvc.z;
    float qd0 = (float)qvd.x, qd1 = (float)qvd.y, qd2 = (float)qvd.z;
    vf2 wA = {w0, w1}, wB = {w2, w3};
    edge_accum_pk(p0, p1, p2, vf2{qa0, qb0}, vf2{qa1, qb1},
                  vf2{qa2, qb2}, wA, a0, a1, a2);
    edge_accum_pk(p0, p1, p2, vf2{qc0, qd0}, vf2{qc1, qd1},
                  vf2{qc2, qd2}, wB, a0, a1, a2);
    wsv += wA + wB;
  }
  float A0 = a0.x + a0.y, A1 = a1.x + a1.y, A2 = a2.x + a2.y;
  float ws = wsv.x + wsv.y;
  A0 += __shfl_xor(A0, 16); A1 += __shfl_xor(A1, 16);
  A2 += __shfl_xor(A2, 16); ws += __shfl_xor(ws, 16);
  A0 += __shfl_xor(A0, 32); A1 += __shfl_xor(A1, 32);
  A2 += __shfl_xor(A2, 32); ws += __shfl_xor(ws, 32);
  if (k == 0) {
    float y0, y1, y2;
    node_step(A0, A1, A2, ws, ps0, ps1, ps2, tsq[c], dsq[c], y0, y1, y2);
    of[ip] = y0; of[ip + 1] = y1; of[ip + 2] = y2;
    if (oh4) {
      vh4 h = {(_Float16)y0, (_Float16)y1, (_Float16)y2, (_Float16)0.f};
      oh4[node * 16 + c] = h;
    }
  }
}

static inline size_t al16(size_t x) { return (x + 15) & ~(size_t)15; }

extern "C" void kernel_launch(void* const* d_in, const int* in_sizes, int n_in,
                              void* d_out, int out_size, void* d_ws, size_t ws_size,
                              hipStream_t stream) {
  const float* nodes = (const float*)d_in[0];  // [N,16,3]
  const float* ew    = (const float*)d_in[1];  // [E]
  const float* tsq   = (const float*)d_in[2];  // [16]
  const float* dsq   = (const float*)d_in[3];  // [16]
  const int*   snd   = (const int*)d_in[4];    // [E]
  const int*   rcv   = (const int*)d_in[5];    // [E]
  float* out = (float*)d_out;

  int E = in_sizes[1];
  int N = in_sizes[0] / 48;

  int NS = (N + (1 << SR_BITS) - 1) >> SR_BITS;  // node subranges (4)
  int NC = (E + (1 << CH_BITS) - 1) >> CH_BITS;  // edge chunks (49)

  // workspace (~24MB): row_start[N+4] | aux | pair 4B [E+15N+64] |
  //   partial2(3.2M) | boffL(9.8M) | pos(E bytes)
  // f16 carve inside partial2+boffL (13.0MB, both dead before their
  // writers): xtmp_h4 [0,6.4M) by flow1 (after fill), nodes_h4 [6.4,12.8M)
  // by scanCD (disjoint from live boffL [3.2,5.65M) and pos [13.0M,..)).
  size_t padN  = (size_t)E + 15 * (size_t)N + 64;  // >= padded total + slack
  size_t rsB   = al16((size_t)(N + 4) * 4);
  size_t auxB  = 512;
  size_t pairB = al16(padN * 4);
  size_t p2B   = al16((size_t)NS * NC << SR_BITS);  // uchar
  size_t xh4B  = al16((size_t)N * 16 * 8);          // one f16x4 buffer
  size_t boffB = al16((size_t)NC * N * 4);
  if (p2B + boffB < 2 * xh4B) boffB = 2 * xh4B - p2B;  // safety

  char* base = (char*)d_ws;
  int*           row_start = (int*)base;
  int*           btot      = (int*)(base + rsB);
  int*           pair      = (int*)(base + rsB + auxB);
  unsigned char* partial2  = (unsigned char*)(base + rsB + auxB + pairB);
  unsigned char* boffL     = partial2 + p2B;
  unsigned char* pos       = boffL + boffB;
  vh4*           xtmp_h4   = (vh4*)partial2;          // dead region after fill
  vh4*           nodes_h4  = (vh4*)(partial2 + xh4B);

  int E4  = E >> 2;
  int nb  = (N + 1023) / 1024;   // tiles (<=64 required; 49 @ N=50K)
  int nb2 = (N + 255) / 256;
  int fbk = (E4 + 511) / 512;
  int nfb = (N + 3) / 4;

  hipMemsetAsync(pair, 0, pairB, stream);  // zero pad slots (w=0, rcv=0)
  lhist_kernel<<<dim3(NC, NS), 256, 0, stream>>>(snd, pos, partial2, E, NC);
  scan1A_kernel<<<nb, 1024, 0, stream>>>(partial2, boffL, row_start, btot, N, NC);
  scanCD_kernel<<<nb2, 256, 0, stream>>>(row_start, btot, nodes, nodes_h4, N, nb);
  fill_kernel<<<fbk, 256, 0, stream>>>((const vi4*)snd, (const vi4*)rcv,
                                       (const vf4*)ew, pos, boffL, row_start,
                                       pair, snd, rcv, ew, N, E);

  // step1: p=nodes(f32), q=nodes_h4 -> writes out(f32 scratch) + xtmp_h4
  // step2: p=out(f32),   q=xtmp_h4  -> overwrites out (final)
  flowp_kernel<<<nfb, 256, 0, stream>>>(nodes_h4, nodes, row_start, pair,
                                        tsq, dsq, out, xtmp_h4, N);
  flowp_kernel<<<nfb, 256, 0, stream>>>(xtmp_h4, out, row_start, pair,
                                        tsq, dsq, out, nullptr, N);
}